// Round 2
// baseline (1424.353 us; speedup 1.0000x reference)
//
#include <hip/hip_runtime.h>
#include <hip/hip_bf16.h>
#include <math.h>

// PhiMoE sparse MoE block. E=8, H=1024, F=2048, T=1024.
// Inputs  (float32): hidden_states [1,1024,1024], gate_w [8,1024],
//   w1 [8,2048,1024], w2 [8,1024,2048], w3 [8,2048,1024]
// Outputs (float32, concat): final [1,1024,1024], router_logits [1024,8]
// R2: thin-M streaming GEMMs. Block = (256-row expert chunk, 64-col weight
// tile), 512 thr / 8 waves, wave owns 32 rows. A-operand loaded direct
// global->reg per lane (x is L2-resident; inter is bf16) — no A staging.
// LDS holds only weight tile dbuf (37K/18K) -> 4 blocks/CU = 32 waves/CU.
// Weights streamed from HBM exactly once -> BW-bound target (~134MB / ~67MB).

#define T_TOK 1024
#define H_DIM 1024
#define F_DIM 2048
#define N_EXP 8
#define JIT 0.01f

#define BK  64
#define LDK 72   // LDS row stride (bf16 elems): conflict-free b64 writes + b128 reads
#define CHUNK 256
#define MT_MAX 16   // sum_e ceil(cnt_e/256) <= 15 for any split of 2048 rows

typedef __bf16 bf16_t;
typedef __bf16 bf16x8 __attribute__((ext_vector_type(8)));
typedef __bf16 bf16x4 __attribute__((ext_vector_type(4)));
typedef float f32x4 __attribute__((ext_vector_type(4)));

__device__ inline bf16x4 cvt4(float4 v) {
    bf16x4 r;
    r[0] = (bf16_t)v.x; r[1] = (bf16_t)v.y; r[2] = (bf16_t)v.z; r[3] = (bf16_t)v.w;
    return r;
}
__device__ inline bf16x8 cvt8(float4 a, float4 b) {
    bf16x8 r;
    r[0] = (bf16_t)a.x; r[1] = (bf16_t)a.y; r[2] = (bf16_t)a.z; r[3] = (bf16_t)a.w;
    r[4] = (bf16_t)b.x; r[5] = (bf16_t)b.y; r[6] = (bf16_t)b.z; r[7] = (bf16_t)b.w;
    return r;
}

// workspace layout (bytes)
#define WS_CNT   0
#define WS_BASE  64
#define WS_TOK   128
#define WS_WGT   (128 + 32768)
#define WS_SLOT  (WS_WGT + 32768)
#define WS_INTER 131072              // bf16 [2048][2048] compacted intermediate (8 MB)
#define WS_ACC   (131072 + 8388608)  // f32  [2][1024][1024] slot accumulators (8 MB)

// ---------------- Router: logits + sparsemixer top-2 ----------------
__global__ __launch_bounds__(256) void router_k(
    const float* __restrict__ x, const float* __restrict__ gw,
    float* __restrict__ logits_out,
    int* __restrict__ cnt, int* __restrict__ tok,
    float* __restrict__ wgt, int* __restrict__ slot)
{
    int t = blockIdx.x;
    int tid = threadIdx.x;
    __shared__ float sm[N_EXP][256];

    float acc[N_EXP];
#pragma unroll
    for (int e = 0; e < N_EXP; e++) acc[e] = 0.f;
#pragma unroll
    for (int j = 0; j < H_DIM / 256; j++) {
        int h = tid + j * 256;
        float xv = x[t * H_DIM + h];
#pragma unroll
        for (int e = 0; e < N_EXP; e++) acc[e] += xv * gw[e * H_DIM + h];
    }
#pragma unroll
    for (int e = 0; e < N_EXP; e++) sm[e][tid] = acc[e];
    __syncthreads();
    for (int s = 128; s > 0; s >>= 1) {
        if (tid < s) {
#pragma unroll
            for (int e = 0; e < N_EXP; e++) sm[e][tid] += sm[e][tid + s];
        }
        __syncthreads();
    }
    if (tid == 0) {
        float s[N_EXP];
#pragma unroll
        for (int e = 0; e < N_EXP; e++) {
            s[e] = sm[e][0];
            logits_out[t * N_EXP + e] = s[e];
        }
        float max1 = -INFINITY; int sel1 = 0;
        for (int e = 0; e < N_EXP; e++) if (s[e] > max1) { max1 = s[e]; sel1 = e; }
        float denom1 = 0.f;
        for (int e = 0; e < N_EXP; e++) {
            float factor = fmaxf(fabsf(s[e]), max1);
            bool m = ((max1 - s[e]) / factor) > (2.0f * JIT);
            if (!m) denom1 += expf(s[e] - max1);
        }
        float mult1 = 1.0f / denom1;
        float max2 = -INFINITY; int sel2 = 0;
        for (int e = 0; e < N_EXP; e++)
            if (e != sel1 && s[e] > max2) { max2 = s[e]; sel2 = e; }
        float denom2 = 0.f;
        for (int e = 0; e < N_EXP; e++) {
            if (e == sel1) continue;
            float factor = fmaxf(fabsf(s[e]), max2);
            bool m = ((max2 - s[e]) / factor) > (2.0f * JIT);
            if (!m) denom2 += expf(s[e] - max2);
        }
        float mult2 = 1.0f / denom2;

        int p1 = atomicAdd(&cnt[sel1], 1);
        tok[sel1 * T_TOK + p1] = t; wgt[sel1 * T_TOK + p1] = mult1; slot[sel1 * T_TOK + p1] = 0;
        int p2 = atomicAdd(&cnt[sel2], 1);
        tok[sel2 * T_TOK + p2] = t; wgt[sel2 * T_TOK + p2] = mult2; slot[sel2 * T_TOK + p2] = 1;
    }
}

__global__ void prefix_k(const int* __restrict__ cnt, int* __restrict__ base)
{
    if (threadIdx.x == 0 && blockIdx.x == 0) {
        int a = 0;
        for (int e = 0; e < N_EXP; e++) { base[e] = a; a += cnt[e]; }
    }
}

// ---------------- GEMM1: inter = silu(x@w1^T) * (x@w3^T) ----------------
// Block: (256-row chunk, 64 cols of w1/w3). 512 thr, 8 waves x 32 rows.
// A direct from global (per-lane row ptr); B dbuf in LDS, streamed once.
__global__ __launch_bounds__(512, 8) void gemm1_k(
    const float* __restrict__ x,
    const float* __restrict__ w1,
    const float* __restrict__ w3,
    const int* __restrict__ cnt, const int* __restrict__ base,
    const int* __restrict__ tok,
    bf16_t* __restrict__ inter)
{
    int mt = blockIdx.x >> 5;       // flat 256-row chunk across experts
    int nt = blockIdx.x & 31;       // 32 n-tiles of 64
    int e = 0, m0 = 0, found = 0, accb = 0;
#pragma unroll
    for (int ee = 0; ee < N_EXP; ee++) {
        int b = (cnt[ee] + 255) >> 8;
        if (!found && mt < accb + b) { e = ee; m0 = (mt - accb) << 8; found = 1; }
        accb += b;
    }
    if (!found) return;
    int cntE = cnt[e];
    int n0 = nt * 64;
    int tid = threadIdx.x;
    int lane = tid & 63, quad = lane >> 4, l16 = lane & 15;
    int wave = tid >> 6;

    __shared__ __align__(16) bf16_t B1l[2][64 * LDK];
    __shared__ __align__(16) bf16_t B3l[2][64 * LDK];
    __shared__ int tokL[CHUNK];

    if (tid < CHUNK) {
        int r = m0 + tid;
        tokL[tid] = tok[e * T_TOK + (r < cntE ? r : cntE - 1)];
    }
    __syncthreads();

    // B staging: 64x64 f32 per matrix = 1024 float4 chunks; 2/thread/matrix
    int rB[2], kB[2];
    const float* b1P[2];
    const float* b3P[2];
    const float* w1e = w1 + (size_t)e * F_DIM * H_DIM + (size_t)n0 * H_DIM;
    const float* w3e = w3 + (size_t)e * F_DIM * H_DIM + (size_t)n0 * H_DIM;
#pragma unroll
    for (int i = 0; i < 2; i++) {
        int c = tid + i * 512;
        rB[i] = c >> 4; kB[i] = c & 15;
        b1P[i] = w1e + (size_t)rB[i] * H_DIM + kB[i] * 4;
        b3P[i] = w3e + (size_t)rB[i] * H_DIM + kB[i] * 4;
    }

    // A: per-lane direct row pointers (wave owns rows wave*32 + i*16 + l16)
    const float* aP[2];
#pragma unroll
    for (int i = 0; i < 2; i++) {
        int rr = wave * 32 + i * 16 + l16;
        aP[i] = x + (size_t)tokL[rr] * H_DIM + quad * 8;
    }

    f32x4 acc1[2][4], acc3[2][4];
#pragma unroll
    for (int i = 0; i < 2; i++)
#pragma unroll
        for (int j = 0; j < 4; j++) {
            acc1[i][j] = f32x4{0.f, 0.f, 0.f, 0.f};
            acc3[i][j] = f32x4{0.f, 0.f, 0.f, 0.f};
        }

    float4 pb1[2], pb3[2];
    float4 pa[2][2][2];   // [rowgrp][subiter][half]
#pragma unroll
    for (int i = 0; i < 2; i++) { pb1[i] = *(const float4*)(b1P[i]); pb3[i] = *(const float4*)(b3P[i]); }
#pragma unroll
    for (int i = 0; i < 2; i++)
#pragma unroll
        for (int s = 0; s < 2; s++) {
            pa[i][s][0] = *(const float4*)(aP[i] + s * 32);
            pa[i][s][1] = *(const float4*)(aP[i] + s * 32 + 4);
        }

    for (int kk = 0; kk < H_DIM / BK; kk++) {
        int buf = kk & 1;
        // stage weight tile (vmcnt waits land on loads issued a full iter ago)
#pragma unroll
        for (int i = 0; i < 2; i++) {
            *(bf16x4*)&B1l[buf][rB[i] * LDK + kB[i] * 4] = cvt4(pb1[i]);
            *(bf16x4*)&B3l[buf][rB[i] * LDK + kB[i] * 4] = cvt4(pb3[i]);
        }
        // consume A prefetch into bf16 frags (frees pa for reissue)
        bf16x8 af[2][2];
#pragma unroll
        for (int i = 0; i < 2; i++)
#pragma unroll
            for (int s = 0; s < 2; s++)
                af[i][s] = cvt8(pa[i][s][0], pa[i][s][1]);
        // issue next iter's loads: B first (needed first next iter), then A
        if (kk + 1 < H_DIM / BK) {
            int k0 = (kk + 1) * BK;
#pragma unroll
            for (int i = 0; i < 2; i++) {
                pb1[i] = *(const float4*)(b1P[i] + k0);
                pb3[i] = *(const float4*)(b3P[i] + k0);
            }
#pragma unroll
            for (int i = 0; i < 2; i++)
#pragma unroll
                for (int s = 0; s < 2; s++) {
                    pa[i][s][0] = *(const float4*)(aP[i] + k0 + s * 32);
                    pa[i][s][1] = *(const float4*)(aP[i] + k0 + s * 32 + 4);
                }
        }
        __syncthreads();
#pragma unroll
        for (int s = 0; s < 2; s++) {
            int ko = s * 32 + quad * 8;
            bf16x8 b1f[4], b3f[4];
#pragma unroll
            for (int j = 0; j < 4; j++) {
                b1f[j] = *(const bf16x8*)&B1l[buf][(j * 16 + l16) * LDK + ko];
                b3f[j] = *(const bf16x8*)&B3l[buf][(j * 16 + l16) * LDK + ko];
            }
#pragma unroll
            for (int i = 0; i < 2; i++)
#pragma unroll
                for (int j = 0; j < 4; j++) {
                    acc1[i][j] = __builtin_amdgcn_mfma_f32_16x16x32_bf16(af[i][s], b1f[j], acc1[i][j], 0, 0, 0);
                    acc3[i][j] = __builtin_amdgcn_mfma_f32_16x16x32_bf16(af[i][s], b3f[j], acc3[i][j], 0, 0, 0);
                }
        }
    }

    int rowBase = base[e];
#pragma unroll
    for (int i = 0; i < 2; i++) {
#pragma unroll
        for (int j = 0; j < 4; j++) {
            int ff = n0 + j * 16 + l16;
#pragma unroll
            for (int r = 0; r < 4; r++) {
                int mm = m0 + wave * 32 + i * 16 + quad * 4 + r;
                if (mm < cntE) {
                    float h1 = acc1[i][j][r], h3 = acc3[i][j][r];
                    float v = (h1 / (1.f + expf(-h1))) * h3;
                    inter[(size_t)(rowBase + mm) * F_DIM + ff] = (bf16_t)v;
                }
            }
        }
    }
}

// ---------------- GEMM2: out = (inter @ w2^T) * wgt, scatter to slot accumulator ----------------
// Block: (256-row chunk, 64 cols of w2). 512 thr, 8 waves x 32 rows.
// A (bf16 inter) direct from global; w2 dbuf in LDS, streamed once.
__global__ __launch_bounds__(512, 8) void gemm2_k(
    const bf16_t* __restrict__ inter,
    const float* __restrict__ w2,
    const int* __restrict__ cnt, const int* __restrict__ base,
    const int* __restrict__ tok,
    const float* __restrict__ wgt, const int* __restrict__ slot,
    float* __restrict__ accOut)
{
    int mt = blockIdx.x >> 4;       // flat 256-row chunk across experts
    int nt = blockIdx.x & 15;       // 16 n-tiles of 64
    int e = 0, m0 = 0, found = 0, accb = 0;
#pragma unroll
    for (int ee = 0; ee < N_EXP; ee++) {
        int b = (cnt[ee] + 255) >> 8;
        if (!found && mt < accb + b) { e = ee; m0 = (mt - accb) << 8; found = 1; }
        accb += b;
    }
    if (!found) return;
    int cntE = cnt[e];
    int n0 = nt * 64;
    int tid = threadIdx.x;
    int lane = tid & 63, quad = lane >> 4, l16 = lane & 15;
    int wave = tid >> 6;
    int rowBase = base[e];

    __shared__ __align__(16) bf16_t Bl[2][64 * LDK];

    // B staging: 64x64 f32 = 1024 float4 chunks; 2/thread
    int rB[2], kB[2];
    const float* bP[2];
    const float* w2e = w2 + (size_t)e * H_DIM * F_DIM + (size_t)n0 * F_DIM;
#pragma unroll
    for (int i = 0; i < 2; i++) {
        int c = tid + i * 512;
        rB[i] = c >> 4; kB[i] = c & 15;
        bP[i] = w2e + (size_t)rB[i] * F_DIM + kB[i] * 4;
    }

    // A: per-lane direct row pointers into compacted bf16 inter
    const bf16_t* aP[2];
#pragma unroll
    for (int i = 0; i < 2; i++) {
        int rr = m0 + wave * 32 + i * 16 + l16;
        if (rr >= cntE) rr = cntE - 1;
        aP[i] = inter + (size_t)(rowBase + rr) * F_DIM + quad * 8;
    }

    f32x4 acc[2][4];
#pragma unroll
    for (int i = 0; i < 2; i++)
#pragma unroll
        for (int j = 0; j < 4; j++) acc[i][j] = f32x4{0.f, 0.f, 0.f, 0.f};

    float4 pb[2];
    bf16x8 pa[2][2];
#pragma unroll
    for (int i = 0; i < 2; i++) pb[i] = *(const float4*)(bP[i]);
#pragma unroll
    for (int i = 0; i < 2; i++)
#pragma unroll
        for (int s = 0; s < 2; s++) pa[i][s] = *(const bf16x8*)(aP[i] + s * 32);

    for (int kk = 0; kk < F_DIM / BK; kk++) {
        int buf = kk & 1;
#pragma unroll
        for (int i = 0; i < 2; i++)
            *(bf16x4*)&Bl[buf][rB[i] * LDK + kB[i] * 4] = cvt4(pb[i]);
        bf16x8 af[2][2];
#pragma unroll
        for (int i = 0; i < 2; i++)
#pragma unroll
            for (int s = 0; s < 2; s++) af[i][s] = pa[i][s];
        if (kk + 1 < F_DIM / BK) {
            int k0 = (kk + 1) * BK;
#pragma unroll
            for (int i = 0; i < 2; i++) pb[i] = *(const float4*)(bP[i] + k0);
#pragma unroll
            for (int i = 0; i < 2; i++)
#pragma unroll
                for (int s = 0; s < 2; s++) pa[i][s] = *(const bf16x8*)(aP[i] + k0 + s * 32);
        }
        __syncthreads();
#pragma unroll
        for (int s = 0; s < 2; s++) {
            int ko = s * 32 + quad * 8;
            bf16x8 bfr[4];
#pragma unroll
            for (int j = 0; j < 4; j++)
                bfr[j] = *(const bf16x8*)&Bl[buf][(j * 16 + l16) * LDK + ko];
#pragma unroll
            for (int i = 0; i < 2; i++)
#pragma unroll
                for (int j = 0; j < 4; j++)
                    acc[i][j] = __builtin_amdgcn_mfma_f32_16x16x32_bf16(af[i][s], bfr[j], acc[i][j], 0, 0, 0);
        }
    }

#pragma unroll
    for (int i = 0; i < 2; i++)
#pragma unroll
        for (int r = 0; r < 4; r++) {
            int mm = m0 + wave * 32 + i * 16 + quad * 4 + r;
            if (mm < cntE) {
                int t = tok[e * T_TOK + mm];
                float wv = wgt[e * T_TOK + mm];
                int sl = slot[e * T_TOK + mm];
                float* dst = accOut + (size_t)sl * T_TOK * H_DIM + (size_t)t * H_DIM;
#pragma unroll
                for (int j = 0; j < 4; j++)
                    dst[n0 + j * 16 + l16] = acc[i][j][r] * wv;
            }
        }
}

// ---------------- combine ----------------
__global__ __launch_bounds__(256) void combine_k(const float* __restrict__ acc,
                                                 float* __restrict__ out)
{
    int i = blockIdx.x * 256 + threadIdx.x;
    const float4* a0 = (const float4*)acc;
    const float4* a1 = (const float4*)(acc + (size_t)T_TOK * H_DIM);
    float4 v0 = a0[i];
    float4 v1 = a1[i];
    float4 r;
    r.x = v0.x + v1.x; r.y = v0.y + v1.y; r.z = v0.z + v1.z; r.w = v0.w + v1.w;
    ((float4*)out)[i] = r;
}

extern "C" void kernel_launch(void* const* d_in, const int* in_sizes, int n_in,
                              void* d_out, int out_size, void* d_ws, size_t ws_size,
                              hipStream_t stream) {
    const float* x  = (const float*)d_in[0];
    const float* gw = (const float*)d_in[1];
    const float* w1 = (const float*)d_in[2];
    const float* w2 = (const float*)d_in[3];
    const float* w3 = (const float*)d_in[4];
    float* out = (float*)d_out;
    float* logits_out = out + (size_t)T_TOK * H_DIM;

    char* ws = (char*)d_ws;
    int*    cnt   = (int*)(ws + WS_CNT);
    int*    basep = (int*)(ws + WS_BASE);
    int*    tok   = (int*)(ws + WS_TOK);
    float*  wgt   = (float*)(ws + WS_WGT);
    int*    slot  = (int*)(ws + WS_SLOT);
    bf16_t* inter = (bf16_t*)(ws + WS_INTER);
    float*  accO  = (float*)(ws + WS_ACC);

    hipMemsetAsync(cnt, 0, 64, stream);
    router_k<<<T_TOK, 256, 0, stream>>>(x, gw, logits_out, cnt, tok, wgt, slot);
    prefix_k<<<1, 64, 0, stream>>>(cnt, basep);
    gemm1_k<<<dim3(MT_MAX * 32), 512, 0, stream>>>(x, w1, w3, cnt, basep, tok, inter);
    gemm2_k<<<dim3(MT_MAX * 16), 512, 0, stream>>>(inter, w2, cnt, basep, tok, wgt, slot, accO);
    combine_k<<<(T_TOK * H_DIM / 4) / 256, 256, 0, stream>>>(accO, out);
}

// Round 3
// 371.323 us; speedup vs baseline: 3.8359x; 3.8359x over previous
//
#include <hip/hip_runtime.h>
#include <hip/hip_bf16.h>
#include <math.h>

// PhiMoE sparse MoE block. E=8, H=1024, F=2048, T=1024.
// Inputs  (float32): hidden_states [1,1024,1024], gate_w [8,1024],
//   w1 [8,2048,1024], w2 [8,1024,2048], w3 [8,2048,1024]
// Outputs (float32, concat): final [1,1024,1024], router_logits [1024,8]
// R3: thin-M streaming GEMMs, register-lean. R2's structure was right but
// __launch_bounds__(512,8) = 8 waves/EU capped VGPR at ~64 -> spill storm
// (VGPR=32, 3.5GB of scratch traffic). Now: 32-col weight tiles (acc 32v/16v),
// A loaded on-demand in the s-loop (x is L2-resident, inter L3-resident),
// only the B HBM stream keeps depth-1 reg prefetch. Peak ~100v under a safe
// __launch_bounds__(512,4) cap of 128 -> 2 blocks/CU, zero spills.
// Weights streamed from HBM exactly once: gemm1 134MB (~22us floor),
// gemm2 67MB (~11us floor).

#define T_TOK 1024
#define H_DIM 1024
#define F_DIM 2048
#define N_EXP 8
#define JIT 0.01f

#define BK  64
#define LDK 72   // LDS row stride (bf16 elems): conflict-free b64 writes + b128 reads
#define CHUNK 256
#define MT_MAX 16   // sum_e ceil(cnt_e/256) <= 15 for any split of 2048 rows

typedef __bf16 bf16_t;
typedef __bf16 bf16x8 __attribute__((ext_vector_type(8)));
typedef __bf16 bf16x4 __attribute__((ext_vector_type(4)));
typedef float f32x4 __attribute__((ext_vector_type(4)));

__device__ inline bf16x4 cvt4(float4 v) {
    bf16x4 r;
    r[0] = (bf16_t)v.x; r[1] = (bf16_t)v.y; r[2] = (bf16_t)v.z; r[3] = (bf16_t)v.w;
    return r;
}
__device__ inline bf16x8 cvt8(float4 a, float4 b) {
    bf16x8 r;
    r[0] = (bf16_t)a.x; r[1] = (bf16_t)a.y; r[2] = (bf16_t)a.z; r[3] = (bf16_t)a.w;
    r[4] = (bf16_t)b.x; r[5] = (bf16_t)b.y; r[6] = (bf16_t)b.z; r[7] = (bf16_t)b.w;
    return r;
}

// workspace layout (bytes)
#define WS_CNT   0
#define WS_BASE  64
#define WS_TOK   128
#define WS_WGT   (128 + 32768)
#define WS_SLOT  (WS_WGT + 32768)
#define WS_INTER 131072              // bf16 [2048][2048] compacted intermediate (8 MB)
#define WS_ACC   (131072 + 8388608)  // f32  [2][1024][1024] slot accumulators (8 MB)

// ---------------- Router: logits + sparsemixer top-2 ----------------
__global__ __launch_bounds__(256) void router_k(
    const float* __restrict__ x, const float* __restrict__ gw,
    float* __restrict__ logits_out,
    int* __restrict__ cnt, int* __restrict__ tok,
    float* __restrict__ wgt, int* __restrict__ slot)
{
    int t = blockIdx.x;
    int tid = threadIdx.x;
    __shared__ float sm[N_EXP][256];

    float acc[N_EXP];
#pragma unroll
    for (int e = 0; e < N_EXP; e++) acc[e] = 0.f;
#pragma unroll
    for (int j = 0; j < H_DIM / 256; j++) {
        int h = tid + j * 256;
        float xv = x[t * H_DIM + h];
#pragma unroll
        for (int e = 0; e < N_EXP; e++) acc[e] += xv * gw[e * H_DIM + h];
    }
#pragma unroll
    for (int e = 0; e < N_EXP; e++) sm[e][tid] = acc[e];
    __syncthreads();
    for (int s = 128; s > 0; s >>= 1) {
        if (tid < s) {
#pragma unroll
            for (int e = 0; e < N_EXP; e++) sm[e][tid] += sm[e][tid + s];
        }
        __syncthreads();
    }
    if (tid == 0) {
        float s[N_EXP];
#pragma unroll
        for (int e = 0; e < N_EXP; e++) {
            s[e] = sm[e][0];
            logits_out[t * N_EXP + e] = s[e];
        }
        float max1 = -INFINITY; int sel1 = 0;
        for (int e = 0; e < N_EXP; e++) if (s[e] > max1) { max1 = s[e]; sel1 = e; }
        float denom1 = 0.f;
        for (int e = 0; e < N_EXP; e++) {
            float factor = fmaxf(fabsf(s[e]), max1);
            bool m = ((max1 - s[e]) / factor) > (2.0f * JIT);
            if (!m) denom1 += expf(s[e] - max1);
        }
        float mult1 = 1.0f / denom1;
        float max2 = -INFINITY; int sel2 = 0;
        for (int e = 0; e < N_EXP; e++)
            if (e != sel1 && s[e] > max2) { max2 = s[e]; sel2 = e; }
        float denom2 = 0.f;
        for (int e = 0; e < N_EXP; e++) {
            if (e == sel1) continue;
            float factor = fmaxf(fabsf(s[e]), max2);
            bool m = ((max2 - s[e]) / factor) > (2.0f * JIT);
            if (!m) denom2 += expf(s[e] - max2);
        }
        float mult2 = 1.0f / denom2;

        int p1 = atomicAdd(&cnt[sel1], 1);
        tok[sel1 * T_TOK + p1] = t; wgt[sel1 * T_TOK + p1] = mult1; slot[sel1 * T_TOK + p1] = 0;
        int p2 = atomicAdd(&cnt[sel2], 1);
        tok[sel2 * T_TOK + p2] = t; wgt[sel2 * T_TOK + p2] = mult2; slot[sel2 * T_TOK + p2] = 1;
    }
}

__global__ void prefix_k(const int* __restrict__ cnt, int* __restrict__ base)
{
    if (threadIdx.x == 0 && blockIdx.x == 0) {
        int a = 0;
        for (int e = 0; e < N_EXP; e++) { base[e] = a; a += cnt[e]; }
    }
}

// ---------------- GEMM1: inter = silu(x@w1^T) * (x@w3^T) ----------------
// Block: (256-row chunk, 32 cols of w1/w3). 512 thr, 8 waves x 32 rows.
// A direct global->reg in the s-loop (L2-resident); B dbuf LDS, streamed once.
__global__ __launch_bounds__(512, 4) void gemm1_k(
    const float* __restrict__ x,
    const float* __restrict__ w1,
    const float* __restrict__ w3,
    const int* __restrict__ cnt, const int* __restrict__ base,
    const int* __restrict__ tok,
    bf16_t* __restrict__ inter)
{
    int mt = blockIdx.x >> 6;       // flat 256-row chunk across experts
    int nt = blockIdx.x & 63;       // 64 n-tiles of 32
    int e = 0, m0 = 0, found = 0, accb = 0;
#pragma unroll
    for (int ee = 0; ee < N_EXP; ee++) {
        int b = (cnt[ee] + 255) >> 8;
        if (!found && mt < accb + b) { e = ee; m0 = (mt - accb) << 8; found = 1; }
        accb += b;
    }
    if (!found) return;
    int cntE = cnt[e];
    int n0 = nt * 32;
    int tid = threadIdx.x;
    int lane = tid & 63, quad = lane >> 4, l16 = lane & 15;
    int wave = tid >> 6;

    __shared__ __align__(16) bf16_t B1l[2][32 * LDK];
    __shared__ __align__(16) bf16_t B3l[2][32 * LDK];
    __shared__ int tokL[CHUNK];

    if (tid < CHUNK) {
        int r = m0 + tid;
        tokL[tid] = tok[e * T_TOK + (r < cntE ? r : cntE - 1)];
    }
    __syncthreads();

    // B staging: 32x64 f32 per matrix = 512 float4 chunks; 1/thread/matrix
    int rB = tid >> 4, kB = tid & 15;
    const float* b1P = w1 + (size_t)e * F_DIM * H_DIM + (size_t)(n0 + rB) * H_DIM + kB * 4;
    const float* b3P = w3 + (size_t)e * F_DIM * H_DIM + (size_t)(n0 + rB) * H_DIM + kB * 4;

    // A: per-lane direct row pointers (wave owns rows wave*32 + i*16 + l16)
    const float* aP[2];
#pragma unroll
    for (int i = 0; i < 2; i++) {
        int rr = wave * 32 + i * 16 + l16;
        aP[i] = x + (size_t)tokL[rr] * H_DIM + quad * 8;
    }

    f32x4 acc1[2][2], acc3[2][2];
#pragma unroll
    for (int i = 0; i < 2; i++)
#pragma unroll
        for (int j = 0; j < 2; j++) {
            acc1[i][j] = f32x4{0.f, 0.f, 0.f, 0.f};
            acc3[i][j] = f32x4{0.f, 0.f, 0.f, 0.f};
        }

    float4 pb1 = *(const float4*)b1P;
    float4 pb3 = *(const float4*)b3P;

    for (int kk = 0; kk < H_DIM / BK; kk++) {
        int buf = kk & 1;
        // stage weight tile (waits on loads issued a full iter ago)
        *(bf16x4*)&B1l[buf][rB * LDK + kB * 4] = cvt4(pb1);
        *(bf16x4*)&B3l[buf][rB * LDK + kB * 4] = cvt4(pb3);
        if (kk + 1 < H_DIM / BK) {
            int k0 = (kk + 1) * BK;
            pb1 = *(const float4*)(b1P + k0);
            pb3 = *(const float4*)(b3P + k0);
        }
        __syncthreads();
#pragma unroll
        for (int s = 0; s < 2; s++) {
            int ka = kk * BK + s * 32;
            int ko = s * 32 + quad * 8;
            // A on-demand: 2 float4 per row-group from L2-resident x
            bf16x8 af[2];
#pragma unroll
            for (int i = 0; i < 2; i++) {
                float4 a0 = *(const float4*)(aP[i] + ka);
                float4 a1 = *(const float4*)(aP[i] + ka + 4);
                af[i] = cvt8(a0, a1);
            }
            bf16x8 b1f[2], b3f[2];
#pragma unroll
            for (int j = 0; j < 2; j++) {
                b1f[j] = *(const bf16x8*)&B1l[buf][(j * 16 + l16) * LDK + ko];
                b3f[j] = *(const bf16x8*)&B3l[buf][(j * 16 + l16) * LDK + ko];
            }
#pragma unroll
            for (int i = 0; i < 2; i++)
#pragma unroll
                for (int j = 0; j < 2; j++) {
                    acc1[i][j] = __builtin_amdgcn_mfma_f32_16x16x32_bf16(af[i], b1f[j], acc1[i][j], 0, 0, 0);
                    acc3[i][j] = __builtin_amdgcn_mfma_f32_16x16x32_bf16(af[i], b3f[j], acc3[i][j], 0, 0, 0);
                }
        }
    }

    int rowBase = base[e];
#pragma unroll
    for (int i = 0; i < 2; i++) {
#pragma unroll
        for (int j = 0; j < 2; j++) {
            int ff = n0 + j * 16 + l16;
#pragma unroll
            for (int r = 0; r < 4; r++) {
                int mm = m0 + wave * 32 + i * 16 + quad * 4 + r;
                if (mm < cntE) {
                    float h1 = acc1[i][j][r], h3 = acc3[i][j][r];
                    float v = (h1 / (1.f + expf(-h1))) * h3;
                    inter[(size_t)(rowBase + mm) * F_DIM + ff] = (bf16_t)v;
                }
            }
        }
    }
}

// ---------------- GEMM2: out = (inter @ w2^T) * wgt, scatter to slot accumulator ----------------
// Block: (256-row chunk, 32 cols of w2). 512 thr, 8 waves x 32 rows.
// A (bf16 inter) direct global->reg in the s-loop; w2 dbuf LDS, streamed once.
__global__ __launch_bounds__(512, 4) void gemm2_k(
    const bf16_t* __restrict__ inter,
    const float* __restrict__ w2,
    const int* __restrict__ cnt, const int* __restrict__ base,
    const int* __restrict__ tok,
    const float* __restrict__ wgt, const int* __restrict__ slot,
    float* __restrict__ accOut)
{
    int mt = blockIdx.x >> 5;       // flat 256-row chunk across experts
    int nt = blockIdx.x & 31;       // 32 n-tiles of 32
    int e = 0, m0 = 0, found = 0, accb = 0;
#pragma unroll
    for (int ee = 0; ee < N_EXP; ee++) {
        int b = (cnt[ee] + 255) >> 8;
        if (!found && mt < accb + b) { e = ee; m0 = (mt - accb) << 8; found = 1; }
        accb += b;
    }
    if (!found) return;
    int cntE = cnt[e];
    int n0 = nt * 32;
    int tid = threadIdx.x;
    int lane = tid & 63, quad = lane >> 4, l16 = lane & 15;
    int wave = tid >> 6;
    int rowBase = base[e];

    __shared__ __align__(16) bf16_t Bl[2][32 * LDK];

    // B staging: 32x64 f32 = 512 float4 chunks; 1/thread
    int rB = tid >> 4, kB = tid & 15;
    const float* bP = w2 + (size_t)e * H_DIM * F_DIM + (size_t)(n0 + rB) * F_DIM + kB * 4;

    // A: per-lane direct row pointers into compacted bf16 inter
    const bf16_t* aP[2];
#pragma unroll
    for (int i = 0; i < 2; i++) {
        int rr = m0 + wave * 32 + i * 16 + l16;
        if (rr >= cntE) rr = cntE - 1;
        aP[i] = inter + (size_t)(rowBase + rr) * F_DIM + quad * 8;
    }

    f32x4 acc[2][2];
#pragma unroll
    for (int i = 0; i < 2; i++)
#pragma unroll
        for (int j = 0; j < 2; j++) acc[i][j] = f32x4{0.f, 0.f, 0.f, 0.f};

    float4 pb = *(const float4*)bP;

    for (int kk = 0; kk < F_DIM / BK; kk++) {
        int buf = kk & 1;
        *(bf16x4*)&Bl[buf][rB * LDK + kB * 4] = cvt4(pb);
        if (kk + 1 < F_DIM / BK) {
            int k0 = (kk + 1) * BK;
            pb = *(const float4*)(bP + k0);
        }
        __syncthreads();
#pragma unroll
        for (int s = 0; s < 2; s++) {
            int ka = kk * BK + s * 32;
            int ko = s * 32 + quad * 8;
            bf16x8 af[2];
#pragma unroll
            for (int i = 0; i < 2; i++)
                af[i] = *(const bf16x8*)(aP[i] + ka);
            bf16x8 bfr[2];
#pragma unroll
            for (int j = 0; j < 2; j++)
                bfr[j] = *(const bf16x8*)&Bl[buf][(j * 16 + l16) * LDK + ko];
#pragma unroll
            for (int i = 0; i < 2; i++)
#pragma unroll
                for (int j = 0; j < 2; j++)
                    acc[i][j] = __builtin_amdgcn_mfma_f32_16x16x32_bf16(af[i], bfr[j], acc[i][j], 0, 0, 0);
        }
    }

#pragma unroll
    for (int i = 0; i < 2; i++)
#pragma unroll
        for (int r = 0; r < 4; r++) {
            int mm = m0 + wave * 32 + i * 16 + quad * 4 + r;
            if (mm < cntE) {
                int t = tok[e * T_TOK + mm];
                float wv = wgt[e * T_TOK + mm];
                int sl = slot[e * T_TOK + mm];
                float* dst = accOut + (size_t)sl * T_TOK * H_DIM + (size_t)t * H_DIM;
#pragma unroll
                for (int j = 0; j < 2; j++)
                    dst[n0 + j * 16 + l16] = acc[i][j][r] * wv;
            }
        }
}

// ---------------- combine ----------------
__global__ __launch_bounds__(256) void combine_k(const float* __restrict__ acc,
                                                 float* __restrict__ out)
{
    int i = blockIdx.x * 256 + threadIdx.x;
    const float4* a0 = (const float4*)acc;
    const float4* a1 = (const float4*)(acc + (size_t)T_TOK * H_DIM);
    float4 v0 = a0[i];
    float4 v1 = a1[i];
    float4 r;
    r.x = v0.x + v1.x; r.y = v0.y + v1.y; r.z = v0.z + v1.z; r.w = v0.w + v1.w;
    ((float4*)out)[i] = r;
}

extern "C" void kernel_launch(void* const* d_in, const int* in_sizes, int n_in,
                              void* d_out, int out_size, void* d_ws, size_t ws_size,
                              hipStream_t stream) {
    const float* x  = (const float*)d_in[0];
    const float* gw = (const float*)d_in[1];
    const float* w1 = (const float*)d_in[2];
    const float* w2 = (const float*)d_in[3];
    const float* w3 = (const float*)d_in[4];
    float* out = (float*)d_out;
    float* logits_out = out + (size_t)T_TOK * H_DIM;

    char* ws = (char*)d_ws;
    int*    cnt   = (int*)(ws + WS_CNT);
    int*    basep = (int*)(ws + WS_BASE);
    int*    tok   = (int*)(ws + WS_TOK);
    float*  wgt   = (float*)(ws + WS_WGT);
    int*    slot  = (int*)(ws + WS_SLOT);
    bf16_t* inter = (bf16_t*)(ws + WS_INTER);
    float*  accO  = (float*)(ws + WS_ACC);

    hipMemsetAsync(cnt, 0, 64, stream);
    router_k<<<T_TOK, 256, 0, stream>>>(x, gw, logits_out, cnt, tok, wgt, slot);
    prefix_k<<<1, 64, 0, stream>>>(cnt, basep);
    gemm1_k<<<dim3(MT_MAX * 64), 512, 0, stream>>>(x, w1, w3, cnt, basep, tok, inter);
    gemm2_k<<<dim3(MT_MAX * 32), 512, 0, stream>>>(inter, w2, cnt, basep, tok, wgt, slot, accO);
    combine_k<<<(T_TOK * H_DIM / 4) / 256, 256, 0, stream>>>(accO, out);
}

// Round 4
// 321.631 us; speedup vs baseline: 4.4285x; 1.1545x over previous
//
#include <hip/hip_runtime.h>
#include <hip/hip_bf16.h>
#include <math.h>

// PhiMoE sparse MoE block. E=8, H=1024, F=2048, T=1024.
// Inputs  (float32): hidden_states [1,1024,1024], gate_w [8,1024],
//   w1 [8,2048,1024], w2 [8,1024,2048], w3 [8,2048,1024]
// Outputs (float32, concat): final [1,1024,1024], router_logits [1024,8]
// R4: counted-vmcnt streaming GEMMs. R1/R3 were latency-bound because
// __syncthreads() lowers to s_waitcnt vmcnt(0) -> every K-iter drained the
// prefetch and serialized a full HBM round-trip (15K cy/iter, HBM at 14%).
// Now: raw s_barrier + asm lgkmcnt(0) only; the compiler's auto waitcnt for
// the staged regs is a COUNTED vmcnt(N) (loads issued one region earlier),
// so the weight stream stays in flight across barriers. A staged coalesced
// in LDS (R3's per-lane-row A loads were 64-line divergent). One barrier
// per K-step (write buf^X and read buf^X in same region, opposite buffers).
// Reg sets double-buffered with static indexing via #pragma unroll 2.

#define T_TOK 1024
#define H_DIM 1024
#define F_DIM 2048
#define N_EXP 8
#define JIT 0.01f

#define BK  64
#define LDK 68   // LDS row stride (bf16): row-to-row = 136B = +2 banks -> <=2-way
#define NK1 (H_DIM / BK)   // 16
#define NK2 (F_DIM / BK)   // 32
#define MT1_MAX 16   // sum_e ceil(cnt_e/256) <= 15
#define MT2_MAX 24   // sum_e ceil(cnt_e/128) <= 24

typedef __bf16 bf16_t;
typedef __bf16 bf16x8 __attribute__((ext_vector_type(8)));
typedef __bf16 bf16x4 __attribute__((ext_vector_type(4)));
typedef float f32x4 __attribute__((ext_vector_type(4)));

__device__ inline bf16x4 cvt4(float4 v) {
    bf16x4 r;
    r[0] = (bf16_t)v.x; r[1] = (bf16_t)v.y; r[2] = (bf16_t)v.z; r[3] = (bf16_t)v.w;
    return r;
}

// workspace layout (bytes)
#define WS_CNT   0
#define WS_BASE  64
#define WS_TOK   128
#define WS_WGT   (128 + 32768)
#define WS_SLOT  (WS_WGT + 32768)
#define WS_INTER 131072              // bf16 [2048][2048] compacted intermediate (8 MB)
#define WS_ACC   (131072 + 8388608)  // f32  [2][1024][1024] slot accumulators (8 MB)

// ---------------- Router: logits + sparsemixer top-2 ----------------
__global__ __launch_bounds__(256) void router_k(
    const float* __restrict__ x, const float* __restrict__ gw,
    float* __restrict__ logits_out,
    int* __restrict__ cnt, int* __restrict__ tok,
    float* __restrict__ wgt, int* __restrict__ slot)
{
    int t = blockIdx.x;
    int tid = threadIdx.x;
    __shared__ float sm[N_EXP][256];

    float acc[N_EXP];
#pragma unroll
    for (int e = 0; e < N_EXP; e++) acc[e] = 0.f;
#pragma unroll
    for (int j = 0; j < H_DIM / 256; j++) {
        int h = tid + j * 256;
        float xv = x[t * H_DIM + h];
#pragma unroll
        for (int e = 0; e < N_EXP; e++) acc[e] += xv * gw[e * H_DIM + h];
    }
#pragma unroll
    for (int e = 0; e < N_EXP; e++) sm[e][tid] = acc[e];
    __syncthreads();
    for (int s = 128; s > 0; s >>= 1) {
        if (tid < s) {
#pragma unroll
            for (int e = 0; e < N_EXP; e++) sm[e][tid] += sm[e][tid + s];
        }
        __syncthreads();
    }
    if (tid == 0) {
        float s[N_EXP];
#pragma unroll
        for (int e = 0; e < N_EXP; e++) {
            s[e] = sm[e][0];
            logits_out[t * N_EXP + e] = s[e];
        }
        float max1 = -INFINITY; int sel1 = 0;
        for (int e = 0; e < N_EXP; e++) if (s[e] > max1) { max1 = s[e]; sel1 = e; }
        float denom1 = 0.f;
        for (int e = 0; e < N_EXP; e++) {
            float factor = fmaxf(fabsf(s[e]), max1);
            bool m = ((max1 - s[e]) / factor) > (2.0f * JIT);
            if (!m) denom1 += expf(s[e] - max1);
        }
        float mult1 = 1.0f / denom1;
        float max2 = -INFINITY; int sel2 = 0;
        for (int e = 0; e < N_EXP; e++)
            if (e != sel1 && s[e] > max2) { max2 = s[e]; sel2 = e; }
        float denom2 = 0.f;
        for (int e = 0; e < N_EXP; e++) {
            if (e == sel1) continue;
            float factor = fmaxf(fabsf(s[e]), max2);
            bool m = ((max2 - s[e]) / factor) > (2.0f * JIT);
            if (!m) denom2 += expf(s[e] - max2);
        }
        float mult2 = 1.0f / denom2;

        int p1 = atomicAdd(&cnt[sel1], 1);
        tok[sel1 * T_TOK + p1] = t; wgt[sel1 * T_TOK + p1] = mult1; slot[sel1 * T_TOK + p1] = 0;
        int p2 = atomicAdd(&cnt[sel2], 1);
        tok[sel2 * T_TOK + p2] = t; wgt[sel2 * T_TOK + p2] = mult2; slot[sel2 * T_TOK + p2] = 1;
    }
}

__global__ void prefix_k(const int* __restrict__ cnt, int* __restrict__ base)
{
    if (threadIdx.x == 0 && blockIdx.x == 0) {
        int a = 0;
        for (int e = 0; e < N_EXP; e++) { base[e] = a; a += cnt[e]; }
    }
}

// ---------------- GEMM1: inter = silu(x@w1^T) * (x@w3^T) ----------------
// Block: 256 rows x (64 w1-cols + 64 w3-cols), BK=64, 512 thr / 8 waves.
// Wave (wm,wn): rows [64*wm,+64), cols [32*wn,+32) of BOTH mats.
// 1 barrier/K-step (raw), counted vmcnt across it. LDS ~105KB -> 1 blk/CU.
__global__ __launch_bounds__(512, 2) void gemm1_k(
    const float* __restrict__ x,
    const float* __restrict__ w1,
    const float* __restrict__ w3,
    const int* __restrict__ cnt, const int* __restrict__ base,
    const int* __restrict__ tok,
    bf16_t* __restrict__ inter)
{
    int mt = blockIdx.x >> 5;       // flat 256-row chunk across experts
    int nt = blockIdx.x & 31;       // 32 n-tiles of 64 (per mat)
    int e = 0, m0 = 0, found = 0, accb = 0;
#pragma unroll
    for (int ee = 0; ee < N_EXP; ee++) {
        int b = (cnt[ee] + 255) >> 8;
        if (!found && mt < accb + b) { e = ee; m0 = (mt - accb) << 8; found = 1; }
        accb += b;
    }
    if (!found) return;
    int cntE = cnt[e];
    int n0 = nt * 64;
    int tid = threadIdx.x;
    int lane = tid & 63, quad = lane >> 4, l16 = lane & 15;
    int wave = tid >> 6;
    int wm = wave >> 1, wn = wave & 1;

    __shared__ __align__(16) bf16_t Al[2][256 * LDK];
    __shared__ __align__(16) bf16_t B1l[2][64 * LDK];
    __shared__ __align__(16) bf16_t B3l[2][64 * LDK];
    __shared__ int tokL[256];

    if (tid < 256) {
        int r = m0 + tid;
        tokL[tid] = tok[e * T_TOK + (r < cntE ? r : cntE - 1)];
    }
    __syncthreads();

    // A staging: 256x64 f32 = 4096 float4, 8/thread (coalesced 64B per row-segment)
    int rA[8], kA[8];
    const float* aP[8];
#pragma unroll
    for (int i = 0; i < 8; i++) {
        int c = tid + i * 512;
        rA[i] = c >> 4; kA[i] = c & 15;
        aP[i] = x + (size_t)tokL[rA[i]] * H_DIM + kA[i] * 4;
    }
    // B staging: 64x64 f32 per mat = 1024 float4, 2/thread/mat
    int rB[2], kB[2];
    const float *b1P[2], *b3P[2];
    const float* w1e = w1 + (size_t)e * F_DIM * H_DIM + (size_t)n0 * H_DIM;
    const float* w3e = w3 + (size_t)e * F_DIM * H_DIM + (size_t)n0 * H_DIM;
#pragma unroll
    for (int i = 0; i < 2; i++) {
        int c = tid + i * 512;
        rB[i] = c >> 4; kB[i] = c & 15;
        b1P[i] = w1e + (size_t)rB[i] * H_DIM + kB[i] * 4;
        b3P[i] = w3e + (size_t)rB[i] * H_DIM + kB[i] * 4;
    }

    f32x4 acc1[4][2], acc3[4][2];
#pragma unroll
    for (int fi = 0; fi < 4; fi++)
#pragma unroll
        for (int fj = 0; fj < 2; fj++) {
            acc1[fi][fj] = f32x4{0.f, 0.f, 0.f, 0.f};
            acc3[fi][fj] = f32x4{0.f, 0.f, 0.f, 0.f};
        }

    // double-set staged registers (static-indexed via unroll-by-2)
    float4 pA[2][8], p1[2][2], p3[2][2];
#pragma unroll
    for (int i = 0; i < 8; i++) pA[0][i] = *(const float4*)(aP[i]);
#pragma unroll
    for (int i = 0; i < 2; i++) { p1[0][i] = *(const float4*)(b1P[i]); p3[0][i] = *(const float4*)(b3P[i]); }

#pragma unroll 2
    for (int kk = 0; kk < NK1; kk++) {
        const int cur = kk & 1, nxt = cur ^ 1;
        // issue next region's loads FIRST -> the ds_write waits below become
        // counted vmcnt(N), and these loads stay in flight across the barrier
        if (kk + 1 < NK1) {
            const int k0 = (kk + 1) * BK;
#pragma unroll
            for (int i = 0; i < 8; i++) pA[nxt][i] = *(const float4*)(aP[i] + k0);
#pragma unroll
            for (int i = 0; i < 2; i++) {
                p1[nxt][i] = *(const float4*)(b1P[i] + k0);
                p3[nxt][i] = *(const float4*)(b3P[i] + k0);
            }
        }
        __builtin_amdgcn_sched_barrier(0);   // pin issue order: loads before stage
        // stage set[cur] (loaded one region ago) into LDS buf[cur]
#pragma unroll
        for (int i = 0; i < 8; i++)
            *(bf16x4*)&Al[cur][rA[i] * LDK + kA[i] * 4] = cvt4(pA[cur][i]);
#pragma unroll
        for (int i = 0; i < 2; i++) {
            *(bf16x4*)&B1l[cur][rB[i] * LDK + kB[i] * 4] = cvt4(p1[cur][i]);
            *(bf16x4*)&B3l[cur][rB[i] * LDK + kB[i] * 4] = cvt4(p3[cur][i]);
        }
        // raw barrier: drain only LDS (lgkm), NOT the in-flight global loads
        asm volatile("s_waitcnt lgkmcnt(0)" ::: "memory");
        __builtin_amdgcn_s_barrier();
        // compute on buf[cur]
#pragma unroll
        for (int s = 0; s < 2; s++) {
            int ko = s * 32 + quad * 8;
            bf16x8 af[4], b1f[2], b3f[2];
#pragma unroll
            for (int fi = 0; fi < 4; fi++)
                af[fi] = *(const bf16x8*)&Al[cur][(wm * 64 + fi * 16 + l16) * LDK + ko];
#pragma unroll
            for (int fj = 0; fj < 2; fj++) {
                b1f[fj] = *(const bf16x8*)&B1l[cur][(wn * 32 + fj * 16 + l16) * LDK + ko];
                b3f[fj] = *(const bf16x8*)&B3l[cur][(wn * 32 + fj * 16 + l16) * LDK + ko];
            }
#pragma unroll
            for (int fi = 0; fi < 4; fi++)
#pragma unroll
                for (int fj = 0; fj < 2; fj++) {
                    acc1[fi][fj] = __builtin_amdgcn_mfma_f32_16x16x32_bf16(af[fi], b1f[fj], acc1[fi][fj], 0, 0, 0);
                    acc3[fi][fj] = __builtin_amdgcn_mfma_f32_16x16x32_bf16(af[fi], b3f[fj], acc3[fi][fj], 0, 0, 0);
                }
        }
    }

    int rowBase = base[e];
#pragma unroll
    for (int fi = 0; fi < 4; fi++)
#pragma unroll
        for (int fj = 0; fj < 2; fj++) {
            int ff = n0 + wn * 32 + fj * 16 + l16;
#pragma unroll
            for (int r = 0; r < 4; r++) {
                int mm = m0 + wm * 64 + fi * 16 + quad * 4 + r;
                if (mm < cntE) {
                    float h1 = acc1[fi][fj][r], h3 = acc3[fi][fj][r];
                    float v = (h1 / (1.f + expf(-h1))) * h3;
                    inter[(size_t)(rowBase + mm) * F_DIM + ff] = (bf16_t)v;
                }
            }
        }
}

// ---------------- GEMM2: out = (inter @ w2^T) * wgt, scatter to slot accumulator ----------------
// Block: 128 rows x 64 cols, BK=64, 512 thr / 8 waves. Wave: 32 rows x 32 cols.
// Same counted-vmcnt pipeline. A (bf16, contiguous compacted rows) coalesced.
__global__ __launch_bounds__(512, 2) void gemm2_k(
    const bf16_t* __restrict__ inter,
    const float* __restrict__ w2,
    const int* __restrict__ cnt, const int* __restrict__ base,
    const int* __restrict__ tok,
    const float* __restrict__ wgt, const int* __restrict__ slot,
    float* __restrict__ accOut)
{
    int mt = blockIdx.x >> 4;       // flat 128-row chunk across experts
    int nt = blockIdx.x & 15;       // 16 n-tiles of 64
    int e = 0, m0 = 0, found = 0, accb = 0;
#pragma unroll
    for (int ee = 0; ee < N_EXP; ee++) {
        int b = (cnt[ee] + 127) >> 7;
        if (!found && mt < accb + b) { e = ee; m0 = (mt - accb) << 7; found = 1; }
        accb += b;
    }
    if (!found) return;
    int cntE = cnt[e];
    int n0 = nt * 64;
    int tid = threadIdx.x;
    int lane = tid & 63, quad = lane >> 4, l16 = lane & 15;
    int wave = tid >> 6;
    int wm = wave >> 1, wn = wave & 1;
    int rowBase = base[e];

    __shared__ __align__(16) bf16_t Al[2][128 * LDK];
    __shared__ __align__(16) bf16_t Bl[2][64 * LDK];

    // A staging: 128x64 bf16 = 1024 bf16x8 chunks, 2/thread
    int rA[2], kA[2];
    const bf16_t* aP[2];
#pragma unroll
    for (int i = 0; i < 2; i++) {
        int c = tid + i * 512;
        rA[i] = c >> 3; kA[i] = c & 7;
        int row = m0 + rA[i]; if (row >= cntE) row = cntE - 1;
        aP[i] = inter + (size_t)(rowBase + row) * F_DIM + kA[i] * 8;
    }
    // B staging: 64x64 f32 = 1024 float4, 2/thread
    int rB[2], kB[2];
    const float* bP[2];
    const float* w2e = w2 + (size_t)e * H_DIM * F_DIM + (size_t)n0 * F_DIM;
#pragma unroll
    for (int i = 0; i < 2; i++) {
        int c = tid + i * 512;
        rB[i] = c >> 4; kB[i] = c & 15;
        bP[i] = w2e + (size_t)rB[i] * F_DIM + kB[i] * 4;
    }

    f32x4 acc[2][2];
#pragma unroll
    for (int fi = 0; fi < 2; fi++)
#pragma unroll
        for (int fj = 0; fj < 2; fj++) acc[fi][fj] = f32x4{0.f, 0.f, 0.f, 0.f};

    bf16x8 pa[2][2];
    float4 pb[2][2];
#pragma unroll
    for (int i = 0; i < 2; i++) { pa[0][i] = *(const bf16x8*)(aP[i]); pb[0][i] = *(const float4*)(bP[i]); }

#pragma unroll 2
    for (int kk = 0; kk < NK2; kk++) {
        const int cur = kk & 1, nxt = cur ^ 1;
        if (kk + 1 < NK2) {
            const int k0 = (kk + 1) * BK;
#pragma unroll
            for (int i = 0; i < 2; i++) {
                pa[nxt][i] = *(const bf16x8*)(aP[i] + k0);
                pb[nxt][i] = *(const float4*)(bP[i] + k0);
            }
        }
        __builtin_amdgcn_sched_barrier(0);
#pragma unroll
        for (int i = 0; i < 2; i++) {
            *(bf16x8*)&Al[cur][rA[i] * LDK + kA[i] * 8] = pa[cur][i];
            *(bf16x4*)&Bl[cur][rB[i] * LDK + kB[i] * 4] = cvt4(pb[cur][i]);
        }
        asm volatile("s_waitcnt lgkmcnt(0)" ::: "memory");
        __builtin_amdgcn_s_barrier();
#pragma unroll
        for (int s = 0; s < 2; s++) {
            int ko = s * 32 + quad * 8;
            bf16x8 af[2], bfr[2];
#pragma unroll
            for (int fi = 0; fi < 2; fi++)
                af[fi] = *(const bf16x8*)&Al[cur][(wm * 32 + fi * 16 + l16) * LDK + ko];
#pragma unroll
            for (int fj = 0; fj < 2; fj++)
                bfr[fj] = *(const bf16x8*)&Bl[cur][(wn * 32 + fj * 16 + l16) * LDK + ko];
#pragma unroll
            for (int fi = 0; fi < 2; fi++)
#pragma unroll
                for (int fj = 0; fj < 2; fj++)
                    acc[fi][fj] = __builtin_amdgcn_mfma_f32_16x16x32_bf16(af[fi], bfr[fj], acc[fi][fj], 0, 0, 0);
        }
    }

#pragma unroll
    for (int fi = 0; fi < 2; fi++)
#pragma unroll
        for (int r = 0; r < 4; r++) {
            int mm = m0 + wm * 32 + fi * 16 + quad * 4 + r;
            if (mm < cntE) {
                int t = tok[e * T_TOK + mm];
                float wv = wgt[e * T_TOK + mm];
                int sl = slot[e * T_TOK + mm];
                float* dst = accOut + (size_t)sl * T_TOK * H_DIM + (size_t)t * H_DIM;
#pragma unroll
                for (int fj = 0; fj < 2; fj++)
                    dst[n0 + wn * 32 + fj * 16 + l16] = acc[fi][fj][r] * wv;
            }
        }
}

// ---------------- combine ----------------
__global__ __launch_bounds__(256) void combine_k(const float* __restrict__ acc,
                                                 float* __restrict__ out)
{
    int i = blockIdx.x * 256 + threadIdx.x;
    const float4* a0 = (const float4*)acc;
    const float4* a1 = (const float4*)(acc + (size_t)T_TOK * H_DIM);
    float4 v0 = a0[i];
    float4 v1 = a1[i];
    float4 r;
    r.x = v0.x + v1.x; r.y = v0.y + v1.y; r.z = v0.z + v1.z; r.w = v0.w + v1.w;
    ((float4*)out)[i] = r;
}

extern "C" void kernel_launch(void* const* d_in, const int* in_sizes, int n_in,
                              void* d_out, int out_size, void* d_ws, size_t ws_size,
                              hipStream_t stream) {
    const float* x  = (const float*)d_in[0];
    const float* gw = (const float*)d_in[1];
    const float* w1 = (const float*)d_in[2];
    const float* w2 = (const float*)d_in[3];
    const float* w3 = (const float*)d_in[4];
    float* out = (float*)d_out;
    float* logits_out = out + (size_t)T_TOK * H_DIM;

    char* ws = (char*)d_ws;
    int*    cnt   = (int*)(ws + WS_CNT);
    int*    basep = (int*)(ws + WS_BASE);
    int*    tok   = (int*)(ws + WS_TOK);
    float*  wgt   = (float*)(ws + WS_WGT);
    int*    slot  = (int*)(ws + WS_SLOT);
    bf16_t* inter = (bf16_t*)(ws + WS_INTER);
    float*  accO  = (float*)(ws + WS_ACC);

    hipMemsetAsync(cnt, 0, 64, stream);
    router_k<<<T_TOK, 256, 0, stream>>>(x, gw, logits_out, cnt, tok, wgt, slot);
    prefix_k<<<1, 64, 0, stream>>>(cnt, basep);
    gemm1_k<<<dim3(MT1_MAX * 32), 512, 0, stream>>>(x, w1, w3, cnt, basep, tok, inter);
    gemm2_k<<<dim3(MT2_MAX * 16), 512, 0, stream>>>(inter, w2, cnt, basep, tok, wgt, slot, accO);
    combine_k<<<(T_TOK * H_DIM / 4) / 256, 256, 0, stream>>>(accO, out);
}

// Round 5
// 314.473 us; speedup vs baseline: 4.5293x; 1.0228x over previous
//
#include <hip/hip_runtime.h>
#include <hip/hip_bf16.h>
#include <math.h>

// PhiMoE sparse MoE block. E=8, H=1024, F=2048, T=1024.
// Inputs  (float32): hidden_states [1,1024,1024], gate_w [8,1024],
//   w1 [8,2048,1024], w2 [8,1024,2048], w3 [8,2048,1024]
// Outputs (float32, concat): final [1,1024,1024], router_logits [1024,8]
// R5: latency-covering schedule with PLAIN __syncthreads:
//   stage(cur) -> __syncthreads -> issue loads(next) -> MFMA(cur)
// At the ds_write the awaited loads were issued before the PREVIOUS MFMA
// phase (already landed); at the barrier zero vmem is outstanding (drain is
// free); new loads cover the MFMA phase. R1/R3/R4 all issued loads right
// before the barrier -> full HBM latency exposed every K-step (~1 TB/s cap).
// Tiles shrunk for co-residency: gemm1 70KB LDS -> 2 blk/CU, gemm2 52KB ->
// 3 blk/CU, so residual latency is hidden by co-resident blocks (m114).
// Router: wave-parallel (1 token/wave, shuffle reduce, no barrier tree).

#define T_TOK 1024
#define H_DIM 1024
#define F_DIM 2048
#define N_EXP 8
#define JIT 0.01f

#define BK  64
#define LDK 68   // bf16 row stride: 136B rows -> 2-way-max bank aliasing (free), 0 conflicts measured in R4
#define NK1 (H_DIM / BK)   // 16
#define NK2 (F_DIM / BK)   // 32
#define MT_MAX 24          // sum_e ceil(cnt_e/128) <= 23

typedef __bf16 bf16_t;
typedef __bf16 bf16x8 __attribute__((ext_vector_type(8)));
typedef __bf16 bf16x4 __attribute__((ext_vector_type(4)));
typedef float f32x4 __attribute__((ext_vector_type(4)));

__device__ inline bf16x4 cvt4(float4 v) {
    bf16x4 r;
    r[0] = (bf16_t)v.x; r[1] = (bf16_t)v.y; r[2] = (bf16_t)v.z; r[3] = (bf16_t)v.w;
    return r;
}

// workspace layout (bytes)
#define WS_CNT   0
#define WS_BASE  64
#define WS_TOK   128
#define WS_WGT   (128 + 32768)
#define WS_SLOT  (WS_WGT + 32768)
#define WS_INTER 131072              // bf16 [2048][2048] compacted intermediate (8 MB)
#define WS_ACC   (131072 + 8388608)  // f32  [2][1024][1024] slot accumulators (8 MB)

// ---------------- Router: logits + sparsemixer top-2 ----------------
// 4 waves/block, 1 token/wave: lane l covers h = l*16..l*16+15 for all 8
// experts, then 6-step shuffle-xor reduce. No LDS, no barrier tree.
__global__ __launch_bounds__(256) void router_k(
    const float* __restrict__ x, const float* __restrict__ gw,
    float* __restrict__ logits_out,
    int* __restrict__ cnt, int* __restrict__ tok,
    float* __restrict__ wgt, int* __restrict__ slot)
{
    int wave = threadIdx.x >> 6, lane = threadIdx.x & 63;
    int t = blockIdx.x * 4 + wave;
    const float* xr = x + (size_t)t * H_DIM;
    int h0 = lane * 16;

    float acc[N_EXP];
#pragma unroll
    for (int e = 0; e < N_EXP; e++) acc[e] = 0.f;
#pragma unroll
    for (int j = 0; j < 16; j += 4) {
        float4 xv = *(const float4*)(xr + h0 + j);
#pragma unroll
        for (int e = 0; e < N_EXP; e++) {
            float4 gv = *(const float4*)(gw + e * H_DIM + h0 + j);
            acc[e] += xv.x * gv.x + xv.y * gv.y + xv.z * gv.z + xv.w * gv.w;
        }
    }
#pragma unroll
    for (int m = 32; m > 0; m >>= 1)
#pragma unroll
        for (int e = 0; e < N_EXP; e++) acc[e] += __shfl_xor(acc[e], m, 64);

    if (lane == 0) {
        float s[N_EXP];
#pragma unroll
        for (int e = 0; e < N_EXP; e++) {
            s[e] = acc[e];
            logits_out[t * N_EXP + e] = s[e];
        }
        float max1 = -INFINITY; int sel1 = 0;
        for (int e = 0; e < N_EXP; e++) if (s[e] > max1) { max1 = s[e]; sel1 = e; }
        float denom1 = 0.f;
        for (int e = 0; e < N_EXP; e++) {
            float factor = fmaxf(fabsf(s[e]), max1);
            bool m = ((max1 - s[e]) / factor) > (2.0f * JIT);
            if (!m) denom1 += expf(s[e] - max1);
        }
        float mult1 = 1.0f / denom1;
        float max2 = -INFINITY; int sel2 = 0;
        for (int e = 0; e < N_EXP; e++)
            if (e != sel1 && s[e] > max2) { max2 = s[e]; sel2 = e; }
        float denom2 = 0.f;
        for (int e = 0; e < N_EXP; e++) {
            if (e == sel1) continue;
            float factor = fmaxf(fabsf(s[e]), max2);
            bool m = ((max2 - s[e]) / factor) > (2.0f * JIT);
            if (!m) denom2 += expf(s[e] - max2);
        }
        float mult2 = 1.0f / denom2;

        int p1 = atomicAdd(&cnt[sel1], 1);
        tok[sel1 * T_TOK + p1] = t; wgt[sel1 * T_TOK + p1] = mult1; slot[sel1 * T_TOK + p1] = 0;
        int p2 = atomicAdd(&cnt[sel2], 1);
        tok[sel2 * T_TOK + p2] = t; wgt[sel2 * T_TOK + p2] = mult2; slot[sel2 * T_TOK + p2] = 1;
    }
}

__global__ void prefix_k(const int* __restrict__ cnt, int* __restrict__ base)
{
    if (threadIdx.x == 0 && blockIdx.x == 0) {
        int a = 0;
        for (int e = 0; e < N_EXP; e++) { base[e] = a; a += cnt[e]; }
    }
}

// ---------------- GEMM1: inter = silu(x@w1^T) * (x@w3^T) ----------------
// Block: 128 rows x 64 cols (both mats), BK=64, 256 thr / 4 waves.
// Wave w: rows [32w,+32). LDS 70KB -> 2 blocks/CU.
__global__ __launch_bounds__(256, 2) void gemm1_k(
    const float* __restrict__ x,
    const float* __restrict__ w1,
    const float* __restrict__ w3,
    const int* __restrict__ cnt, const int* __restrict__ base,
    const int* __restrict__ tok,
    bf16_t* __restrict__ inter)
{
    int mt = blockIdx.x >> 5;       // flat 128-row chunk across experts
    int nt = blockIdx.x & 31;       // 32 n-tiles of 64
    int e = 0, m0 = 0, found = 0, accb = 0;
#pragma unroll
    for (int ee = 0; ee < N_EXP; ee++) {
        int b = (cnt[ee] + 127) >> 7;
        if (!found && mt < accb + b) { e = ee; m0 = (mt - accb) << 7; found = 1; }
        accb += b;
    }
    if (!found) return;
    int cntE = cnt[e];
    int n0 = nt * 64;
    int tid = threadIdx.x;
    int lane = tid & 63, quad = lane >> 4, l16 = lane & 15;
    int wave = tid >> 6;

    __shared__ __align__(16) bf16_t Al[2][128 * LDK];
    __shared__ __align__(16) bf16_t B1l[2][64 * LDK];
    __shared__ __align__(16) bf16_t B3l[2][64 * LDK];
    __shared__ int tokL[128];

    if (tid < 128) {
        int r = m0 + tid;
        tokL[tid] = tok[e * T_TOK + (r < cntE ? r : cntE - 1)];
    }
    __syncthreads();

    // A staging: 128x64 f32 = 2048 float4, 8/thread
    int rA[8], kA[8], ofsA[8];
#pragma unroll
    for (int i = 0; i < 8; i++) {
        int c = tid + i * 256;
        rA[i] = c >> 4; kA[i] = c & 15;
        ofsA[i] = tokL[rA[i]] * H_DIM + kA[i] * 4;
    }
    // B staging: 64x64 f32 per mat = 1024 float4, 4/thread/mat
    int rB[4], kB[4], ofsB[4];
    const float* w1e = w1 + (size_t)e * F_DIM * H_DIM;
    const float* w3e = w3 + (size_t)e * F_DIM * H_DIM;
#pragma unroll
    for (int i = 0; i < 4; i++) {
        int c = tid + i * 256;
        rB[i] = c >> 4; kB[i] = c & 15;
        ofsB[i] = (n0 + rB[i]) * H_DIM + kB[i] * 4;
    }

    f32x4 acc1[2][4], acc3[2][4];
#pragma unroll
    for (int fi = 0; fi < 2; fi++)
#pragma unroll
        for (int fj = 0; fj < 4; fj++) {
            acc1[fi][fj] = f32x4{0.f, 0.f, 0.f, 0.f};
            acc3[fi][fj] = f32x4{0.f, 0.f, 0.f, 0.f};
        }

    float4 pA[8], p1[4], p3[4];
#pragma unroll
    for (int i = 0; i < 8; i++) pA[i] = *(const float4*)(x + ofsA[i]);
#pragma unroll
    for (int i = 0; i < 4; i++) {
        p1[i] = *(const float4*)(w1e + ofsB[i]);
        p3[i] = *(const float4*)(w3e + ofsB[i]);
    }

#pragma unroll 2
    for (int kk = 0; kk < NK1; kk++) {
        const int cur = kk & 1;
        // stage set loaded one region ago (its loads landed during prev MFMA)
#pragma unroll
        for (int i = 0; i < 8; i++)
            *(bf16x4*)&Al[cur][rA[i] * LDK + kA[i] * 4] = cvt4(pA[i]);
#pragma unroll
        for (int i = 0; i < 4; i++) {
            *(bf16x4*)&B1l[cur][rB[i] * LDK + kB[i] * 4] = cvt4(p1[i]);
            *(bf16x4*)&B3l[cur][rB[i] * LDK + kB[i] * 4] = cvt4(p3[i]);
        }
        __syncthreads();   // zero vmem outstanding here -> drain is free
        // issue next tile's loads AFTER the barrier: MFMA below covers latency
        if (kk + 1 < NK1) {
            const int k0 = (kk + 1) * BK;
#pragma unroll
            for (int i = 0; i < 8; i++) pA[i] = *(const float4*)(x + ofsA[i] + k0);
#pragma unroll
            for (int i = 0; i < 4; i++) {
                p1[i] = *(const float4*)(w1e + ofsB[i] + k0);
                p3[i] = *(const float4*)(w3e + ofsB[i] + k0);
            }
        }
#pragma unroll
        for (int s = 0; s < 2; s++) {
            int ko = s * 32 + quad * 8;
            bf16x8 af[2], b1f[4], b3f[4];
#pragma unroll
            for (int fi = 0; fi < 2; fi++)
                af[fi] = *(const bf16x8*)&Al[cur][(wave * 32 + fi * 16 + l16) * LDK + ko];
#pragma unroll
            for (int fj = 0; fj < 4; fj++) {
                b1f[fj] = *(const bf16x8*)&B1l[cur][(fj * 16 + l16) * LDK + ko];
                b3f[fj] = *(const bf16x8*)&B3l[cur][(fj * 16 + l16) * LDK + ko];
            }
#pragma unroll
            for (int fi = 0; fi < 2; fi++)
#pragma unroll
                for (int fj = 0; fj < 4; fj++) {
                    acc1[fi][fj] = __builtin_amdgcn_mfma_f32_16x16x32_bf16(af[fi], b1f[fj], acc1[fi][fj], 0, 0, 0);
                    acc3[fi][fj] = __builtin_amdgcn_mfma_f32_16x16x32_bf16(af[fi], b3f[fj], acc3[fi][fj], 0, 0, 0);
                }
        }
    }

    int rowBase = base[e];
#pragma unroll
    for (int fi = 0; fi < 2; fi++)
#pragma unroll
        for (int fj = 0; fj < 4; fj++) {
            int ff = n0 + fj * 16 + l16;
#pragma unroll
            for (int r = 0; r < 4; r++) {
                int mm = m0 + wave * 32 + fi * 16 + quad * 4 + r;
                if (mm < cntE) {
                    float h1 = acc1[fi][fj][r], h3 = acc3[fi][fj][r];
                    float v = (h1 / (1.f + expf(-h1))) * h3;
                    inter[(size_t)(rowBase + mm) * F_DIM + ff] = (bf16_t)v;
                }
            }
        }
}

// ---------------- GEMM2: out = (inter @ w2^T) * wgt, scatter to slot accumulator ----------------
// Block: 128 rows x 64 cols, BK=64, 256 thr / 4 waves. LDS 52KB -> 3 blk/CU.
__global__ __launch_bounds__(256, 3) void gemm2_k(
    const bf16_t* __restrict__ inter,
    const float* __restrict__ w2,
    const int* __restrict__ cnt, const int* __restrict__ base,
    const int* __restrict__ tok,
    const float* __restrict__ wgt, const int* __restrict__ slot,
    float* __restrict__ accOut)
{
    int mt = blockIdx.x >> 4;       // flat 128-row chunk across experts
    int nt = blockIdx.x & 15;       // 16 n-tiles of 64
    int e = 0, m0 = 0, found = 0, accb = 0;
#pragma unroll
    for (int ee = 0; ee < N_EXP; ee++) {
        int b = (cnt[ee] + 127) >> 7;
        if (!found && mt < accb + b) { e = ee; m0 = (mt - accb) << 7; found = 1; }
        accb += b;
    }
    if (!found) return;
    int cntE = cnt[e];
    int n0 = nt * 64;
    int tid = threadIdx.x;
    int lane = tid & 63, quad = lane >> 4, l16 = lane & 15;
    int wave = tid >> 6;
    int rowBase = base[e];

    __shared__ __align__(16) bf16_t Al[2][128 * LDK];
    __shared__ __align__(16) bf16_t Bl[2][64 * LDK];

    // A staging: 128x64 bf16 = 1024 bf16x8, 4/thread
    int rA[4], kA[4], ofsA[4];
#pragma unroll
    for (int i = 0; i < 4; i++) {
        int c = tid + i * 256;
        rA[i] = c >> 3; kA[i] = c & 7;
        int row = m0 + rA[i]; if (row >= cntE) row = cntE - 1;
        ofsA[i] = (rowBase + row) * F_DIM + kA[i] * 8;
    }
    // B staging: 64x64 f32 = 1024 float4, 4/thread
    int rB[4], kB[4], ofsB[4];
    const float* w2e = w2 + (size_t)e * H_DIM * F_DIM;
#pragma unroll
    for (int i = 0; i < 4; i++) {
        int c = tid + i * 256;
        rB[i] = c >> 4; kB[i] = c & 15;
        ofsB[i] = (n0 + rB[i]) * F_DIM + kB[i] * 4;
    }

    f32x4 acc[2][4];
#pragma unroll
    for (int fi = 0; fi < 2; fi++)
#pragma unroll
        for (int fj = 0; fj < 4; fj++) acc[fi][fj] = f32x4{0.f, 0.f, 0.f, 0.f};

    bf16x8 pa[4];
    float4 pb[4];
#pragma unroll
    for (int i = 0; i < 4; i++) {
        pa[i] = *(const bf16x8*)(inter + ofsA[i]);
        pb[i] = *(const float4*)(w2e + ofsB[i]);
    }

#pragma unroll 2
    for (int kk = 0; kk < NK2; kk++) {
        const int cur = kk & 1;
#pragma unroll
        for (int i = 0; i < 4; i++) {
            *(bf16x8*)&Al[cur][rA[i] * LDK + kA[i] * 8] = pa[i];
            *(bf16x4*)&Bl[cur][rB[i] * LDK + kB[i] * 4] = cvt4(pb[i]);
        }
        __syncthreads();
        if (kk + 1 < NK2) {
            const int k0 = (kk + 1) * BK;
#pragma unroll
            for (int i = 0; i < 4; i++) {
                pa[i] = *(const bf16x8*)(inter + ofsA[i] + k0);
                pb[i] = *(const float4*)(w2e + ofsB[i] + k0);
            }
        }
#pragma unroll
        for (int s = 0; s < 2; s++) {
            int ko = s * 32 + quad * 8;
            bf16x8 af[2], bfr[4];
#pragma unroll
            for (int fi = 0; fi < 2; fi++)
                af[fi] = *(const bf16x8*)&Al[cur][(wave * 32 + fi * 16 + l16) * LDK + ko];
#pragma unroll
            for (int fj = 0; fj < 4; fj++)
                bfr[fj] = *(const bf16x8*)&Bl[cur][(fj * 16 + l16) * LDK + ko];
#pragma unroll
            for (int fi = 0; fi < 2; fi++)
#pragma unroll
                for (int fj = 0; fj < 4; fj++)
                    acc[fi][fj] = __builtin_amdgcn_mfma_f32_16x16x32_bf16(af[fi], bfr[fj], acc[fi][fj], 0, 0, 0);
        }
    }

#pragma unroll
    for (int fi = 0; fi < 2; fi++)
#pragma unroll
        for (int r = 0; r < 4; r++) {
            int mm = m0 + wave * 32 + fi * 16 + quad * 4 + r;
            if (mm < cntE) {
                int t = tok[e * T_TOK + mm];
                float wv = wgt[e * T_TOK + mm];
                int sl = slot[e * T_TOK + mm];
                float* dst = accOut + (size_t)sl * T_TOK * H_DIM + (size_t)t * H_DIM;
#pragma unroll
                for (int fj = 0; fj < 4; fj++)
                    dst[n0 + fj * 16 + l16] = acc[fi][fj][r] * wv;
            }
        }
}

// ---------------- combine ----------------
__global__ __launch_bounds__(256) void combine_k(const float* __restrict__ acc,
                                                 float* __restrict__ out)
{
    int i = blockIdx.x * 256 + threadIdx.x;
    const float4* a0 = (const float4*)acc;
    const float4* a1 = (const float4*)(acc + (size_t)T_TOK * H_DIM);
    float4 v0 = a0[i];
    float4 v1 = a1[i];
    float4 r;
    r.x = v0.x + v1.x; r.y = v0.y + v1.y; r.z = v0.z + v1.z; r.w = v0.w + v1.w;
    ((float4*)out)[i] = r;
}

extern "C" void kernel_launch(void* const* d_in, const int* in_sizes, int n_in,
                              void* d_out, int out_size, void* d_ws, size_t ws_size,
                              hipStream_t stream) {
    const float* x  = (const float*)d_in[0];
    const float* gw = (const float*)d_in[1];
    const float* w1 = (const float*)d_in[2];
    const float* w2 = (const float*)d_in[3];
    const float* w3 = (const float*)d_in[4];
    float* out = (float*)d_out;
    float* logits_out = out + (size_t)T_TOK * H_DIM;

    char* ws = (char*)d_ws;
    int*    cnt   = (int*)(ws + WS_CNT);
    int*    basep = (int*)(ws + WS_BASE);
    int*    tok   = (int*)(ws + WS_TOK);
    float*  wgt   = (float*)(ws + WS_WGT);
    int*    slot  = (int*)(ws + WS_SLOT);
    bf16_t* inter = (bf16_t*)(ws + WS_INTER);
    float*  accO  = (float*)(ws + WS_ACC);

    hipMemsetAsync(cnt, 0, 64, stream);
    router_k<<<T_TOK / 4, 256, 0, stream>>>(x, gw, logits_out, cnt, tok, wgt, slot);
    prefix_k<<<1, 64, 0, stream>>>(cnt, basep);
    gemm1_k<<<dim3(MT_MAX * 32), 256, 0, stream>>>(x, w1, w3, cnt, basep, tok, inter);
    gemm2_k<<<dim3(MT_MAX * 16), 256, 0, stream>>>(inter, w2, cnt, basep, tok, wgt, slot, accO);
    combine_k<<<(T_TOK * H_DIM / 4) / 256, 256, 0, stream>>>(accO, out);
}